// Round 6
// baseline (5743.697 us; speedup 1.0000x reference)
//
#include <hip/hip_runtime.h>
#include <hip/hip_cooperative_groups.h>

namespace cg = cooperative_groups;
typedef unsigned long long ull;

#define N0_ 100000
#define N1_ 50000
#define N2_ 25000
#define N3_ 12500
#define EDG 1600000
#define CAP1 600000
#define CAP2 200000
#define CAP3 80000

#define HALF_BYTES 51200000ULL   // N0_*128*4 = half of a big fp64 buffer

struct Sel { ull prefix; int remaining; };

__device__ inline int imin_(int a, int b) { return a < b ? a : b; }

// exclusive scan of v across the 256-thread block via LDS; optionally writes
// block total to *blocktot (by tid 255). ired must be 256 ints.
__device__ inline int blk_scan_excl(int v, int* ired, int tid, int* blocktot) {
  ired[tid] = v; __syncthreads();
  for (int d = 1; d < 256; d <<= 1) {
    int t2 = (tid >= d) ? ired[tid - d] : 0;
    __syncthreads();
    ired[tid] += t2;
    __syncthreads();
  }
  int incl = ired[tid];
  if (blocktot && tid == 255) *blocktot = incl;
  __syncthreads();
  return incl - v;
}

// block 0 scans 256 per-block partials blk[src..src+256) -> exclusive blk[dst..),
// total optionally to *totptr.
__device__ inline void blk0_scan_partials(int* blk, int* ired, int tid, bool isb0,
                                          int src, int dst, int* totptr) {
  if (isb0) {
    int v = blk[src + tid];
    ired[tid] = v; __syncthreads();
    for (int d = 1; d < 256; d <<= 1) {
      int t2 = (tid >= d) ? ired[tid - d] : 0;
      __syncthreads();
      ired[tid] += t2;
      __syncthreads();
    }
    blk[dst + tid] = ired[tid] - v;
    if (totptr && tid == 255) *totptr = ired[255];
    __syncthreads();
  }
}

// ---------------- kernels ----------------

__global__ void sentinel_k(float* o, float v) { if (threadIdx.x == 0) o[0] = v; }

// C[n,128] = A[rowidx?[row]][*] @ W (+bias), ACC-typed accumulate. 64 rows/block.
template <typename TA, typename TC, typename ACC>
__global__ __launch_bounds__(256) void matmul128(const TA* __restrict__ A,
    const int* __restrict__ rowidx,
    const float* __restrict__ W, const float* __restrict__ bias,
    TC* __restrict__ C, int n) {
  __shared__ ACC Al[64 * 33];
  __shared__ ACC Wl[32 * 128];
  int tid = threadIdx.x;
  int colb = tid & 31;
  int rg = tid >> 5;
  int row0 = blockIdx.x * 64;
  ACC acc[8][4];
#pragma unroll
  for (int r = 0; r < 8; ++r)
#pragma unroll
    for (int j = 0; j < 4; ++j) acc[r][j] = (ACC)0;
  for (int kt = 0; kt < 128; kt += 32) {
    for (int i = tid; i < 64 * 32; i += 256) {
      int r = i >> 5, kk = i & 31;
      int row = row0 + r;
      ACC v = (ACC)0;
      if (row < n) {
        int ar = rowidx ? rowidx[row] : row;
        v = (ACC)A[(size_t)ar * 128 + kt + kk];
      }
      Al[r * 33 + kk] = v;
    }
    for (int i = tid; i < 32 * 128; i += 256) {
      int kk = i >> 7, c = i & 127;
      Wl[i] = (ACC)W[(size_t)(kt + kk) * 128 + c];
    }
    __syncthreads();
#pragma unroll 4
    for (int kk = 0; kk < 32; ++kk) {
      ACC b0 = Wl[kk * 128 + colb];
      ACC b1 = Wl[kk * 128 + colb + 32];
      ACC b2 = Wl[kk * 128 + colb + 64];
      ACC b3 = Wl[kk * 128 + colb + 96];
#pragma unroll
      for (int r = 0; r < 8; ++r) {
        ACC a = Al[(rg * 8 + r) * 33 + kk];
        acc[r][0] += a * b0; acc[r][1] += a * b1;
        acc[r][2] += a * b2; acc[r][3] += a * b3;
      }
    }
    __syncthreads();
  }
  ACC bb0 = 0, bb1 = 0, bb2 = 0, bb3 = 0;
  if (bias) {
    bb0 = (ACC)bias[colb]; bb1 = (ACC)bias[colb + 32];
    bb2 = (ACC)bias[colb + 64]; bb3 = (ACC)bias[colb + 96];
  }
  for (int r = 0; r < 8; ++r) {
    int row = row0 + rg * 8 + r;
    if (row < n) {
      size_t o = (size_t)row * 128 + colb;
      C[o] = (TC)(acc[r][0] + bb0); C[o + 32] = (TC)(acc[r][1] + bb1);
      C[o + 64] = (TC)(acc[r][2] + bb2); C[o + 96] = (TC)(acc[r][3] + bb3);
    }
  }
}

// y[i,c] = di * sum_p h[src_p,c]*csrw[p] + h[i,c]*dgi[i] + b[c]   (unroll-8)
template <typename TH, typename TY, bool RELU>
__global__ __launch_bounds__(256) void agg_conv(const TH* __restrict__ h,
    const int* __restrict__ off, const int* __restrict__ csrc,
    const double* __restrict__ csrw,
    const double* __restrict__ dinv, const double* __restrict__ dgi,
    const float* __restrict__ bias, TY* __restrict__ y, int n) {
  int c = threadIdx.x & 127;
  int node = blockIdx.x * 2 + (threadIdx.x >> 7);
  if (node >= n) return;
  double di = dinv[node];
  double self = (double)h[(size_t)node * 128 + c] * dgi[node];
  double accA = 0.0, accB = 0.0;
  int p = off[node], p1 = off[node + 1];
  for (; p + 8 <= p1; p += 8) {
    int s0 = csrc[p + 0], s1 = csrc[p + 1], s2 = csrc[p + 2], s3 = csrc[p + 3];
    int s4 = csrc[p + 4], s5 = csrc[p + 5], s6 = csrc[p + 6], s7 = csrc[p + 7];
    double w0 = csrw[p + 0], w1 = csrw[p + 1], w2 = csrw[p + 2], w3 = csrw[p + 3];
    double w4 = csrw[p + 4], w5 = csrw[p + 5], w6 = csrw[p + 6], w7 = csrw[p + 7];
    double v0 = (double)h[(size_t)s0 * 128 + c];
    double v1 = (double)h[(size_t)s1 * 128 + c];
    double v2 = (double)h[(size_t)s2 * 128 + c];
    double v3 = (double)h[(size_t)s3 * 128 + c];
    double v4 = (double)h[(size_t)s4 * 128 + c];
    double v5 = (double)h[(size_t)s5 * 128 + c];
    double v6 = (double)h[(size_t)s6 * 128 + c];
    double v7 = (double)h[(size_t)s7 * 128 + c];
    accA += v0 * w0; accB += v1 * w1; accA += v2 * w2; accB += v3 * w3;
    accA += v4 * w4; accB += v5 * w5; accA += v6 * w6; accB += v7 * w7;
  }
  for (; p + 4 <= p1; p += 4) {
    int s0 = csrc[p + 0], s1 = csrc[p + 1], s2 = csrc[p + 2], s3 = csrc[p + 3];
    double w0 = csrw[p + 0], w1 = csrw[p + 1], w2 = csrw[p + 2], w3 = csrw[p + 3];
    double v0 = (double)h[(size_t)s0 * 128 + c];
    double v1 = (double)h[(size_t)s1 * 128 + c];
    double v2 = (double)h[(size_t)s2 * 128 + c];
    double v3 = (double)h[(size_t)s3 * 128 + c];
    accA += v0 * w0; accB += v1 * w1; accA += v2 * w2; accB += v3 * w3;
  }
  for (; p < p1; ++p)
    accA += (double)h[(size_t)csrc[p] * 128 + c] * csrw[p];
  double r = (accA + accB) * di + self + (bias ? (double)bias[c] : 0.0);
  if (RELU) r = r > 0.0 ? r : 0.0;
  y[(size_t)node * 128 + c] = (TY)r;
}

__global__ void scatter_add_rows(float* __restrict__ h, const float* __restrict__ t,
                                 const int* __restrict__ idx, int k) {
  int i = blockIdx.x * 256 + threadIdx.x;
  if (i < k * 128) h[(size_t)idx[i >> 7] * 128 + (i & 127)] += t[i];
}

// ---- cooperative: level-0 CSR build (replaces 6 dispatches) ----
struct Csr0Args {
  const int* src; const int* dst; int m; int n;
  int* degcnt; int* cursor; int* blk;
  int* csro; int* csrs; double* csrw;
  double* dinv; double* dgi;
};

__global__ __launch_bounds__(256) void csr0_coop(Csr0Args a) {
  cg::grid_group grid = cg::this_grid();
  __shared__ int ired[256];
  const int tid = threadIdx.x, bid = blockIdx.x;
  const int gtid = bid * 256 + tid;
  const int NTH = gridDim.x * 256;
  for (int i = gtid; i < a.n; i += NTH) { a.degcnt[i] = 0; a.cursor[i] = 0; }
  grid.sync();
  for (int e = gtid; e < a.m; e += NTH) atomicAdd(&a.degcnt[a.dst[e]], 1);
  grid.sync();
  int C = (a.n + NTH - 1) / NTH;
  int lo = gtid * C, hi = imin_(a.n, lo + C);
  int mys = 0;
  for (int i = lo; i < hi; ++i) {
    int dg = a.degcnt[i];
    double dd = 1.0 + (double)dg;
    a.dinv[i] = 1.0 / sqrt(dd);
    a.dgi[i] = 1.0 / dd;
    mys += dg;
  }
  int ex = blk_scan_excl(mys, ired, tid, &a.blk[bid]);
  grid.sync();
  blk0_scan_partials(a.blk, ired, tid, bid == 0, 0, 256, &a.csro[a.n]);
  grid.sync();
  int run = a.blk[256 + bid] + ex;
  for (int i = lo; i < hi; ++i) { a.csro[i] = run; run += a.degcnt[i]; }
  grid.sync();
  for (int e = gtid; e < a.m; e += NTH) {
    int d = a.dst[e], s = a.src[e];
    int pos = a.csro[d] + atomicAdd(&a.cursor[d], 1);
    a.csrs[pos] = s;
    a.csrw[pos] = a.dinv[s];
  }
}

// ---- cooperative: BN + scores + exact top-k + next-level CSR (one launch) ----
struct PoolArgs {
  double* x; int n; int k;
  const float* g; const float* beta; float* snap;
  const float* pw;
  ull* keys; int* hist; Sel* sel; int* blk;
  double* bns; double* ssb;
  int* kept; int* knid; int* idx;
  const int* off; const int* csrs;
  int* ndeg; int* noff; int* ncsrs; double* ncsrw; double* ndinv; double* ndgi;
};

__global__ __launch_bounds__(256) void pool_coop(PoolArgs a) {
  cg::grid_group grid = cg::this_grid();
  __shared__ double dred[256];
  __shared__ int ired[256];
  const int tid = threadIdx.x, bid = blockIdx.x;
  const int gtid = bid * 256 + tid;
  const int NTH = gridDim.x * 256;
  const int c = tid & 127, half = tid >> 7;

  // BN stats (deterministic per-block partials, same order as R5)
  {
    double s = 0, q = 0;
    for (int row = bid * 2 + half; row < a.n; row += 512) {
      double v = a.x[(size_t)row * 128 + c];
      s += v; q += v * v;
    }
    dred[tid] = s; __syncthreads();
    double s2 = (half == 0) ? dred[c] + dred[c + 128] : 0.0;
    __syncthreads();
    dred[tid] = q; __syncthreads();
    double q2 = (half == 0) ? dred[c] + dred[c + 128] : 0.0;
    if (half == 0) { a.bns[bid * 256 + c] = s2; a.bns[bid * 256 + 128 + c] = q2; }
  }
  grid.sync();
  if (bid == 0 && tid < 128) {
    double s = 0, q = 0;
    for (int b = 0; b < 256; ++b) { s += a.bns[b * 256 + tid]; q += a.bns[b * 256 + 128 + tid]; }
    double invn = 1.0 / (double)a.n;
    double m = s * invn, v = q * invn - m * m;
    double sc = (double)a.g[tid] / sqrt(v + 1e-5);
    a.ssb[tid] = sc;
    a.ssb[128 + tid] = (double)a.beta[tid] - m * sc;
  }
  if (gtid < 8 * 256) a.hist[gtid] = 0;
  if (gtid == 0) { a.sel->prefix = 0ULL; a.sel->remaining = a.k; }
  grid.sync();
  // BN apply + ReLU + fp32 snapshot
  {
    size_t total = (size_t)a.n * 128;
    for (size_t i = gtid; i < total; i += (size_t)NTH) {
      int cc = (int)(i & 127);
      double v = a.x[i] * a.ssb[cc] + a.ssb[128 + cc];
      v = v > 0.0 ? v : 0.0;
      a.x[i] = v;
      a.snap[i] = (float)v;
    }
  }
  grid.sync();
  // scores -> order-preserving ull keys
  {
    double wv = (tid < 128) ? (double)a.pw[tid] * (double)a.pw[tid] : 0.0;
    dred[tid] = wv; __syncthreads();
    for (int s = 128; s > 0; s >>= 1) { if (tid < s) dred[tid] += dred[tid + s]; __syncthreads(); }
    double wnorm = sqrt(dred[0]);
    __syncthreads();
    for (int node = bid * 2 + half; node < a.n; node += 512) {
      dred[tid] = a.x[(size_t)node * 128 + c] * (double)a.pw[c];
      __syncthreads();
      for (int s = 64; s > 0; s >>= 1) { if (c < s) dred[tid] += dred[tid + s]; __syncthreads(); }
      if (c == 0) {
        double sc = tanh(dred[tid] / wnorm);
        ull u = (ull)__double_as_longlong(sc);
        u = (u >> 63) ? ~u : (u | 0x8000000000000000ULL);
        a.keys[node] = u;
      }
      __syncthreads();
    }
  }
  grid.sync();
  // 8-pass radix select (MSB-first) for exact k-th key
  for (int p = 0; p < 8; ++p) {
    int shift = 56 - 8 * p;
    ired[tid] = 0; __syncthreads();
    ull prefix = a.sel->prefix;
    for (int i = gtid; i < a.n; i += NTH) {
      ull kk = a.keys[i];
      bool ok = (p == 0) || (((kk ^ prefix) >> (shift + 8)) == 0);
      if (ok) atomicAdd(&ired[(int)((kk >> shift) & 255)], 1);
    }
    __syncthreads();
    if (ired[tid]) atomicAdd(&a.hist[p * 256 + tid], ired[tid]);
    grid.sync();
    if (bid == 0 && tid == 0) {
      int rem = a.sel->remaining;
      ull pre = a.sel->prefix;
      for (int b = 255; b >= 0; --b) {
        int cb = a.hist[p * 256 + b];
        if (cb >= rem) { pre |= ((ull)b) << shift; break; }
        rem -= cb;
      }
      a.sel->prefix = pre; a.sel->remaining = rem;
    }
    grid.sync();
  }
  const ull prefix = a.sel->prefix;
  const int rem = a.sel->remaining;
  // eq-rank grid scan -> kept flags (ties broken by ascending index, = jax top_k)
  int C = (a.n + NTH - 1) / NTH;
  int lo = gtid * C, hiE = imin_(a.n, lo + C);
  int myeq = 0;
  for (int i = lo; i < hiE; ++i) myeq += (a.keys[i] == prefix) ? 1 : 0;
  int exEq = blk_scan_excl(myeq, ired, tid, &a.blk[bid]);
  grid.sync();
  blk0_scan_partials(a.blk, ired, tid, bid == 0, 0, 256, nullptr);
  grid.sync();
  int eqbase = a.blk[256 + bid] + exEq;
  int mykept = 0;
  for (int i = lo; i < hiE; ++i) {
    ull u = a.keys[i];
    bool eq = (u == prefix);
    bool kp = (u > prefix) || (eq && eqbase < rem);
    if (eq) ++eqbase;
    a.kept[i] = kp ? 1 : 0;
    mykept += kp ? 1 : 0;
  }
  // kept grid scan -> knid / idx
  int exK = blk_scan_excl(mykept, ired, tid, &a.blk[512 + bid]);
  grid.sync();
  blk0_scan_partials(a.blk, ired, tid, bid == 0, 512, 768, nullptr);
  grid.sync();
  int nid = a.blk[768 + bid] + exK;
  for (int i = lo; i < hiE; ++i) {
    if (a.kept[i]) { a.knid[i] = nid; a.idx[nid] = i; ++nid; }
    else a.knid[i] = -1;
  }
  grid.sync();
  // next-level CSR: degrees
  for (int d = gtid; d < a.n; d += NTH) {
    int nd = a.knid[d];
    if (nd >= 0) {
      int cnt = 0, p1 = a.off[d + 1];
      for (int p = a.off[d]; p < p1; ++p) cnt += (a.knid[a.csrs[p]] >= 0) ? 1 : 0;
      a.ndeg[nd] = cnt;
    }
  }
  grid.sync();
  // fin_deg + offset scan over k
  int C2 = (a.k + NTH - 1) / NTH;
  int lo2 = gtid * C2, hi2 = imin_(a.k, lo2 + C2);
  int mys = 0;
  for (int i = lo2; i < hi2; ++i) {
    int dg = a.ndeg[i];
    double dd = 1.0 + (double)dg;
    a.ndinv[i] = 1.0 / sqrt(dd);
    a.ndgi[i] = 1.0 / dd;
    mys += dg;
  }
  int ex3 = blk_scan_excl(mys, ired, tid, &a.blk[bid]);
  grid.sync();
  blk0_scan_partials(a.blk, ired, tid, bid == 0, 0, 256, &a.noff[a.k]);
  grid.sync();
  int run = a.blk[256 + bid] + ex3;
  for (int i = lo2; i < hi2; ++i) { a.noff[i] = run; run += a.ndeg[i]; }
  grid.sync();
  // fill
  for (int d = gtid; d < a.n; d += NTH) {
    int nd = a.knid[d];
    if (nd >= 0) {
      int pos = a.noff[nd];
      int p1 = a.off[d + 1];
      for (int p = a.off[d]; p < p1; ++p) {
        int s = a.knid[a.csrs[p]];
        if (s >= 0) { a.ncsrs[pos] = s; a.ncsrw[pos] = a.ndinv[s]; ++pos; }
      }
    }
  }
}

// ---- cooperative: fp32 BN (up path), 3 dispatches -> 1 ----
struct BnArgs { float* x; int n; const float* g; const float* beta; double* bns; double* ssb; };

__global__ __launch_bounds__(256) void bn_coop(BnArgs a) {
  cg::grid_group grid = cg::this_grid();
  __shared__ double dred[256];
  const int tid = threadIdx.x, bid = blockIdx.x;
  const int gtid = bid * 256 + tid;
  const int NTH = gridDim.x * 256;
  const int c = tid & 127, half = tid >> 7;
  {
    double s = 0, q = 0;
    for (int row = bid * 2 + half; row < a.n; row += 512) {
      double v = (double)a.x[(size_t)row * 128 + c];
      s += v; q += v * v;
    }
    dred[tid] = s; __syncthreads();
    double s2 = (half == 0) ? dred[c] + dred[c + 128] : 0.0;
    __syncthreads();
    dred[tid] = q; __syncthreads();
    double q2 = (half == 0) ? dred[c] + dred[c + 128] : 0.0;
    if (half == 0) { a.bns[bid * 256 + c] = s2; a.bns[bid * 256 + 128 + c] = q2; }
  }
  grid.sync();
  if (bid == 0 && tid < 128) {
    double s = 0, q = 0;
    for (int b = 0; b < 256; ++b) { s += a.bns[b * 256 + tid]; q += a.bns[b * 256 + 128 + tid]; }
    double invn = 1.0 / (double)a.n;
    double m = s * invn, v = q * invn - m * m;
    double sc = (double)a.g[tid] / sqrt(v + 1e-5);
    a.ssb[tid] = sc;
    a.ssb[128 + tid] = (double)a.beta[tid] - m * sc;
  }
  grid.sync();
  size_t total = (size_t)a.n * 128;
  for (size_t i = gtid; i < total; i += (size_t)NTH) {
    int cc = (int)(i & 127);
    double v = (double)a.x[i] * a.ssb[cc] + a.ssb[128 + cc];
    a.x[i] = (float)(v > 0.0 ? v : 0.0);
  }
}

// ---------------- host ----------------

extern "C" void kernel_launch(void* const* d_in, const int* in_sizes, int n_in,
                              void* d_out, int out_size, void* d_ws, size_t ws_size,
                              hipStream_t stream) {
  (void)in_sizes; (void)out_size;
  if (n_in < 17) return;
  const float* x_in   = (const float*)d_in[0];
  const int*   ei     = (const int*)  d_in[1];
  const float* in_W   = (const float*)d_in[2];
  const float* in_b   = (const float*)d_in[3];
  const float* dn_W   = (const float*)d_in[4];
  const float* dn_b   = (const float*)d_in[5];
  const float* dn_g   = (const float*)d_in[6];
  const float* dn_bt  = (const float*)d_in[7];
  const float* pool_w = (const float*)d_in[8];
  const float* bot_W  = (const float*)d_in[9];
  const float* bot_b  = (const float*)d_in[10];
  const float* up_W   = (const float*)d_in[11];
  const float* up_b   = (const float*)d_in[12];
  const float* up_g   = (const float*)d_in[13];
  const float* up_bt  = (const float*)d_in[14];
  const float* out_W  = (const float*)d_in[15];
  const float* out_b  = (const float*)d_in[16];
  float* outp = (float*)d_out;

  char* base = (char*)d_ws;
  size_t off = 0;
  auto alloc = [&](size_t b) -> void* {
    void* r = base + off;
    off = (off + b + 255) & ~(size_t)255;
    return r;
  };
  double* bufA = (double*)alloc((size_t)N0_ * 128 * 8);
  double* bufB = (double*)alloc((size_t)N0_ * 128 * 8);
  float* xs0f = (float*)((char*)bufB + HALF_BYTES);   // 51.2 MB (B upper half)
  float* xs1f = (float*)((char*)bufA + HALF_BYTES);   // 25.6 MB (A[51.2,76.8))
  float* xs2f = (float*)((char*)bufA + HALF_BYTES + 25600000ULL); // 12.8 MB

  int* csrs0 = (int*)alloc((size_t)EDG * 4);
  int* csrs1 = (int*)alloc((size_t)CAP1 * 4);
  int* csrs2 = (int*)alloc((size_t)CAP2 * 4);
  int* csrs3 = (int*)alloc((size_t)CAP3 * 4);
  double* csrw0 = (double*)alloc((size_t)EDG * 8);
  double* csrw1 = (double*)alloc((size_t)CAP1 * 8);
  double* csrw2 = (double*)alloc((size_t)CAP2 * 8);
  double* csrw3 = (double*)alloc((size_t)CAP3 * 8);
  int* csro0 = (int*)alloc((size_t)(N0_ + 1) * 4);
  int* csro1 = (int*)alloc((size_t)(N1_ + 1) * 4);
  int* csro2 = (int*)alloc((size_t)(N2_ + 1) * 4);
  int* csro3 = (int*)alloc((size_t)(N3_ + 1) * 4);
  double* dinv0 = (double*)alloc((size_t)N0_ * 8); double* dgi0 = (double*)alloc((size_t)N0_ * 8);
  double* dinv1 = (double*)alloc((size_t)N1_ * 8); double* dgi1 = (double*)alloc((size_t)N1_ * 8);
  double* dinv2 = (double*)alloc((size_t)N2_ * 8); double* dgi2 = (double*)alloc((size_t)N2_ * 8);
  double* dinv3 = (double*)alloc((size_t)N3_ * 8); double* dgi3 = (double*)alloc((size_t)N3_ * 8);
  ull* keys = (ull*)alloc((size_t)N0_ * 8);
  int* kept  = (int*)alloc((size_t)N0_ * 4);
  int* knid  = (int*)alloc((size_t)N0_ * 4);
  int* degcnt = (int*)alloc((size_t)N0_ * 4);
  int* cursor = (int*)alloc((size_t)N0_ * 4);
  int* idx0 = (int*)alloc((size_t)N1_ * 4);
  int* idx1 = (int*)alloc((size_t)N2_ * 4);
  int* idx2 = (int*)alloc((size_t)N3_ * 4);
  int* hist = (int*)alloc(8 * 256 * 4);
  Sel* sel  = (Sel*)alloc(256);
  int* blk  = (int*)alloc(1024 * 4);
  double* bns = (double*)alloc((size_t)256 * 256 * 8);
  double* ssb = (double*)alloc(256 * 8);
  if (off > ws_size) {
    sentinel_k<<<1, 64, 0, stream>>>(outp, (float)ws_size);
    return;
  }

  const int nL[4] = {N0_, N1_, N2_, N3_};
  int* csrsL[4] = {csrs0, csrs1, csrs2, csrs3};
  double* csrwL[4] = {csrw0, csrw1, csrw2, csrw3};
  int* csroL[4] = {csro0, csro1, csro2, csro3};
  double* dinvL[4] = {dinv0, dinv1, dinv2, dinv3};
  double* dgiL[4]  = {dgi0, dgi1, dgi2, dgi3};
  int* idxL[3] = {idx0, idx1, idx2};

  auto cdiv = [](int a, int b) { return (a + b - 1) / b; };
  dim3 g256(256), b256(256);

  auto launch_pool = [&](int i, double* x, float* snap) {
    PoolArgs pa;
    pa.x = x; pa.n = nL[i]; pa.k = nL[i + 1];
    pa.g = dn_g + i * 128; pa.beta = dn_bt + i * 128; pa.snap = snap;
    pa.pw = pool_w + i * 128;
    pa.keys = keys; pa.hist = hist; pa.sel = sel; pa.blk = blk;
    pa.bns = bns; pa.ssb = ssb;
    pa.kept = kept; pa.knid = knid; pa.idx = idxL[i];
    pa.off = csroL[i]; pa.csrs = csrsL[i];
    pa.ndeg = degcnt; pa.noff = csroL[i + 1]; pa.ncsrs = csrsL[i + 1];
    pa.ncsrw = csrwL[i + 1]; pa.ndinv = dinvL[i + 1]; pa.ndgi = dgiL[i + 1];
    void* params[] = { &pa };
    hipLaunchCooperativeKernel((void*)pool_coop, g256, b256, params, 0, stream);
  };
  auto launch_bn = [&](float* x, int n, const float* g, const float* bt) {
    BnArgs ba; ba.x = x; ba.n = n; ba.g = g; ba.beta = bt; ba.bns = bns; ba.ssb = ssb;
    void* params[] = { &ba };
    hipLaunchCooperativeKernel((void*)bn_coop, g256, b256, params, 0, stream);
  };

  // ---- level 0 CSR (one cooperative launch) ----
  {
    Csr0Args ca;
    ca.src = ei; ca.dst = ei + EDG; ca.m = EDG; ca.n = N0_;
    ca.degcnt = degcnt; ca.cursor = cursor; ca.blk = blk;
    ca.csro = csro0; ca.csrs = csrs0; ca.csrw = csrw0;
    ca.dinv = dinv0; ca.dgi = dgi0;
    void* params[] = { &ca };
    hipLaunchCooperativeKernel((void*)csr0_coop, g256, b256, params, 0, stream);
  }

  // ---- initial conv (agg-first) ----
  agg_conv<float, double, false><<<cdiv(N0_, 2), 256, 0, stream>>>(
      x_in, csro0, csrs0, csrw0, dinv0, dgi0, nullptr, bufB, N0_);
  matmul128<double, double, double><<<cdiv(N0_, 64), 256, 0, stream>>>(
      bufB, nullptr, in_W, in_b, bufA, N0_);

  // ---- down level 0 ----
  matmul128<double, double, double><<<cdiv(N0_, 64), 256, 0, stream>>>(
      bufA, nullptr, dn_W, nullptr, bufB, N0_);
  agg_conv<double, double, false><<<cdiv(N0_, 2), 256, 0, stream>>>(
      bufB, csro0, csrs0, csrw0, dinv0, dgi0, dn_b, bufA, N0_);
  launch_pool(0, bufA, xs0f);

  // ---- down level 1: matmul gathers pooled rows via idx0 ----
  matmul128<double, double, double><<<cdiv(N1_, 64), 256, 0, stream>>>(
      bufA, idx0, dn_W + 16384, nullptr, bufB, N1_);
  agg_conv<double, double, false><<<cdiv(N1_, 2), 256, 0, stream>>>(
      bufB, csro1, csrs1, csrw1, dinv1, dgi1, dn_b + 128, bufA, N1_);
  launch_pool(1, bufA, xs1f);

  // ---- down level 2 ----
  matmul128<double, double, double><<<cdiv(N2_, 64), 256, 0, stream>>>(
      bufA, idx1, dn_W + 32768, nullptr, bufB, N2_);
  agg_conv<double, double, false><<<cdiv(N2_, 2), 256, 0, stream>>>(
      bufB, csro2, csrs2, csrw2, dinv2, dgi2, dn_b + 256, bufA, N2_);
  launch_pool(2, bufA, xs2f);

  // ---- bottom ----
  matmul128<double, double, double><<<cdiv(N3_, 64), 256, 0, stream>>>(
      bufA, idx2, bot_W, nullptr, bufB, N3_);
  float* zf = (float*)bufA;
  float* hf = (float*)bufB;
  float* tf = outp;  // d_out as scratch until final write (fully overwritten)
  agg_conv<double, float, true><<<cdiv(N3_, 2), 256, 0, stream>>>(
      bufB, csro3, csrs3, csrw3, dinv3, dgi3, bot_b, zf, N3_);

  // ---- up path (fp32) ----
  for (int u = 0; u < 3; ++u) {
    int l = 2 - u;
    int nl = nL[l], nz = nL[l + 1];
    const float* Wt = up_W + u * 32768;
    const float* Wb = up_W + u * 32768 + 16384;
    const float* xsf = (u == 0) ? xs2f : (u == 1) ? xs1f : xs0f;
    matmul128<float, float, float><<<cdiv(nz, 64), 256, 0, stream>>>(
        zf, nullptr, Wt, nullptr, tf, nz);
    matmul128<float, float, float><<<cdiv(nl, 64), 256, 0, stream>>>(
        xsf, nullptr, Wb, nullptr, hf, nl);
    scatter_add_rows<<<cdiv(nz * 128, 256), 256, 0, stream>>>(hf, tf, idxL[l], nz);
    agg_conv<float, float, false><<<cdiv(nl, 2), 256, 0, stream>>>(
        hf, csroL[l], csrsL[l], csrwL[l], dinvL[l], dgiL[l], up_b + u * 128, zf, nl);
    launch_bn(zf, nl, up_g + u * 128, up_bt + u * 128);
  }

  // ---- final conv -> d_out ----
  matmul128<float, float, float><<<cdiv(N0_, 64), 256, 0, stream>>>(
      zf, nullptr, out_W, nullptr, hf, N0_);
  agg_conv<float, float, false><<<cdiv(N0_, 2), 256, 0, stream>>>(
      hf, csro0, csrs0, csrw0, dinv0, dgi0, out_b, outp, N0_);
}